// Round 1
// baseline (2057.611 us; speedup 1.0000x reference)
//
#include <hip/hip_runtime.h>
#include <math.h>

#define NN   20000
#define EE   320000
#define RR   4
#define HH   4
#define DINC 256
#define OUTC 64

static __device__ __forceinline__ float lrelu(float v){ return v > 0.f ? v : 0.2f*v; }

// ---------------- CSR build (original edges only; self-loops handled in GAT kernel) ----------------
__global__ void k_zero_int(int* __restrict__ p, int n){
  int i = blockIdx.x*blockDim.x + threadIdx.x;
  if (i < n) p[i] = 0;
}

__global__ void k_count(const int* __restrict__ dst, int e, int* __restrict__ cnt){
  int i = blockIdx.x*blockDim.x + threadIdx.x;
  if (i < e) atomicAdd(&cnt[dst[i]], 1);
}

__global__ __launch_bounds__(1024) void k_scan(const int* __restrict__ cnt, int* __restrict__ off,
                                               int* __restrict__ cur, int n){
  __shared__ int part[1024];
  int t = threadIdx.x;
  int chunk = (n + 1023) >> 10;
  int lo = t*chunk; if (lo > n) lo = n;
  int hi = lo + chunk; if (hi > n) hi = n;
  int s = 0;
  for (int i = lo; i < hi; ++i) s += cnt[i];
  part[t] = s;
  __syncthreads();
  for (int d = 1; d < 1024; d <<= 1) {
    int u = (t >= d) ? part[t-d] : 0;
    __syncthreads();
    part[t] += u;
    __syncthreads();
  }
  int run = (t == 0) ? 0 : part[t-1];
  for (int i = lo; i < hi; ++i) { off[i] = run; cur[i] = run; run += cnt[i]; }
  if (t == 1023) off[n] = part[1023];
}

__global__ void k_scatter(const int* __restrict__ src, const int* __restrict__ dst, int e,
                          int* __restrict__ cur, int* __restrict__ csr){
  int i = blockIdx.x*blockDim.x + threadIdx.x;
  if (i < e) {
    int p = atomicAdd(&cur[dst[i]], 1);
    csr[p] = src[i];
  }
}

// ---------------- tiled f32 GEMM:  C = act(A0@B0 [+ A1@B1] [+ bias]) ----------------
// A row-major [M,K], B row-major [K,Nc], C row-major ldc. BM=BN=64, BK=16, 256 thr, 4x4 microtile.
#define BM 64
#define BN 64
#define BK 16
#define LDT 68   // +4 pad: keeps 16B alignment, breaks bank conflicts

__global__ __launch_bounds__(256) void k_gemm(
    const float* __restrict__ A0, const float* __restrict__ B0,
    const float* __restrict__ A1, const float* __restrict__ B1,
    const float* __restrict__ bias, float* __restrict__ C,
    int M, int K, int Nc, int ldc, int relu)
{
  __shared__ float As[BK][LDT];
  __shared__ float Bs[BK][LDT];
  int t  = threadIdx.x;
  int tm = t >> 4, tn = t & 15;
  int bm = blockIdx.x * BM, bn = blockIdx.y * BN;
  float acc[4][4] = {};
  int npair = (A1 != nullptr) ? 2 : 1;
  for (int p = 0; p < npair; ++p) {
    const float* __restrict__ A = p ? A1 : A0;
    const float* __restrict__ B = p ? B1 : B0;
    for (int k0 = 0; k0 < K; k0 += BK) {
      #pragma unroll
      for (int i = 0; i < 4; ++i) {            // A tile 64x16 -> As[c][r]
        int e = t + 256*i;
        int r = e >> 4, c = e & 15;
        int row = bm + r;
        As[c][r] = (row < M) ? A[(size_t)row*K + k0 + c] : 0.f;
      }
      #pragma unroll
      for (int i = 0; i < 4; ++i) {            // B tile 16x64 -> Bs[r][c]
        int e = t + 256*i;
        int r = e >> 6, c = e & 63;
        Bs[r][c] = B[(size_t)(k0 + r)*Nc + bn + c];
      }
      __syncthreads();
      #pragma unroll
      for (int k = 0; k < BK; ++k) {
        float4 a = *reinterpret_cast<const float4*>(&As[k][tm*4]);
        float4 b = *reinterpret_cast<const float4*>(&Bs[k][tn*4]);
        float av[4] = {a.x, a.y, a.z, a.w};
        float bv[4] = {b.x, b.y, b.z, b.w};
        #pragma unroll
        for (int i = 0; i < 4; ++i)
          #pragma unroll
          for (int j = 0; j < 4; ++j)
            acc[i][j] += av[i]*bv[j];
      }
      __syncthreads();
    }
  }
  #pragma unroll
  for (int i = 0; i < 4; ++i) {
    int row = bm + tm*4 + i;
    if (row >= M) continue;
    float4 o;
    float* po = &o.x;
    #pragma unroll
    for (int j = 0; j < 4; ++j) {
      int col = bn + tn*4 + j;
      float v = acc[i][j];
      if (bias) v += bias[col];
      if (relu) v = fmaxf(v, 0.f);
      po[j] = v;
    }
    *reinterpret_cast<float4*>(&C[(size_t)row*ldc + bn + tn*4]) = o;
  }
}

// ---------------- GATv2 attention: one wave per dst node, online softmax ----------------
// lane l: head h = l>>4, channels 4*(l&15)..+3  => flat float4 at offset l*4 of the 256-wide row.
__global__ __launch_bounds__(256) void k_gat(
    const float* __restrict__ xl, const float* __restrict__ xr,
    const float* __restrict__ att, const float* __restrict__ bias,
    const int* __restrict__ off, const int* __restrict__ csr,
    float* __restrict__ out, int n)
{
  int node = blockIdx.x*4 + (threadIdx.x >> 6);
  if (node >= n) return;
  int lane = threadIdx.x & 63;
  const float4 xrd = *reinterpret_cast<const float4*>(xr + (size_t)node*256 + lane*4);
  const float4 av  = *reinterpret_cast<const float4*>(att + lane*4);
  float m = -INFINITY, s = 0.f;
  float a0 = 0.f, a1 = 0.f, a2 = 0.f, a3 = 0.f;
  int e0 = off[node], e1 = off[node+1];
  // k = e0-1 is the implicit self-loop (src = node), then the real in-edges
  for (int k = e0 - 1; k < e1; ++k) {
    int src = (k < e0) ? node : csr[k];
    const float4 xls = *reinterpret_cast<const float4*>(xl + (size_t)src*256 + lane*4);
    float z0 = lrelu(xls.x + xrd.x);
    float z1 = lrelu(xls.y + xrd.y);
    float z2 = lrelu(xls.z + xrd.z);
    float z3 = lrelu(xls.w + xrd.w);
    float part = av.x*z0 + av.y*z1 + av.z*z2 + av.w*z3;
    part += __shfl_xor(part, 1);
    part += __shfl_xor(part, 2);
    part += __shfl_xor(part, 4);
    part += __shfl_xor(part, 8);     // per-16-lane-group head logit
    float mn = fmaxf(m, part);
    float sc = __expf(m - mn);       // m=-inf first iter -> 0
    float pw = __expf(part - mn);
    s  = s*sc + pw;
    a0 = a0*sc + pw*xls.x;
    a1 = a1*sc + pw*xls.y;
    a2 = a2*sc + pw*xls.z;
    a3 = a3*sc + pw*xls.w;
    m = mn;
  }
  float inv = 1.f / s;
  const float4 bv = *reinterpret_cast<const float4*>(bias + lane*4);
  float4 o;
  o.x = fmaxf(a0*inv + bv.x, 0.f);   // both GAT layers have ReLU after
  o.y = fmaxf(a1*inv + bv.y, 0.f);
  o.z = fmaxf(a2*inv + bv.z, 0.f);
  o.w = fmaxf(a3*inv + bv.w, 0.f);
  *reinterpret_cast<float4*>(out + (size_t)node*256 + lane*4) = o;
}

// ---------------- GraphConv neighbor sum over CSR (no self loops) ----------------
__global__ __launch_bounds__(256) void k_agg256(const float* __restrict__ x, const int* __restrict__ off,
                                                const int* __restrict__ csr, float* __restrict__ out, int n)
{
  int node = blockIdx.x*4 + (threadIdx.x >> 6);
  if (node >= n) return;
  int lane = threadIdx.x & 63;
  float a0 = 0.f, a1 = 0.f, a2 = 0.f, a3 = 0.f;
  int e1 = off[node+1];
  for (int k = off[node]; k < e1; ++k) {
    const float4 v = *reinterpret_cast<const float4*>(x + (size_t)csr[k]*256 + lane*4);
    a0 += v.x; a1 += v.y; a2 += v.z; a3 += v.w;
  }
  float4 o = {a0, a1, a2, a3};
  *reinterpret_cast<float4*>(out + (size_t)node*256 + lane*4) = o;
}

__global__ __launch_bounds__(256) void k_agg64(const float* __restrict__ x, const int* __restrict__ off,
                                               const int* __restrict__ csr, float* __restrict__ out, int n)
{
  int node = blockIdx.x*4 + (threadIdx.x >> 6);
  if (node >= n) return;
  int lane = threadIdx.x & 63;
  float a = 0.f;
  int e1 = off[node+1];
  for (int k = off[node]; k < e1; ++k) a += x[(size_t)csr[k]*64 + lane];
  out[(size_t)node*64 + lane] = a;
}

// ---------------- orchestration ----------------
extern "C" void kernel_launch(void* const* d_in, const int* in_sizes, int n_in,
                              void* d_out, int out_size, void* d_ws, size_t ws_size,
                              hipStream_t stream)
{
  const float* x      = (const float*)d_in[0];
  const int*   ei     = (const int*)  d_in[1];
  const float* Wl1    = (const float*)d_in[2];
  const float* Wr1    = (const float*)d_in[3];
  const float* att1   = (const float*)d_in[4];
  const float* b1     = (const float*)d_in[5];
  const float* Wl2    = (const float*)d_in[6];
  const float* Wr2    = (const float*)d_in[7];
  const float* att2   = (const float*)d_in[8];
  const float* b2     = (const float*)d_in[9];
  const float* Wrel3  = (const float*)d_in[10];
  const float* Wroot3 = (const float*)d_in[11];
  const float* b3     = (const float*)d_in[12];
  const float* Wrel4  = (const float*)d_in[13];
  const float* Wroot4 = (const float*)d_in[14];
  const float* b4     = (const float*)d_in[15];
  float* out = (float*)d_out;

  const size_t NB = (size_t)NN * 256;   // 5.12M floats per buffer
  float* bufA = (float*)d_ws;
  float* bufB = bufA + NB;
  float* bufC = bufB + NB;
  int* deg = (int*)(bufC + NB);
  int* off = deg + NN;        // NN+1
  int* cur = off + NN + 1;
  int* csr = cur + NN;        // EE

  const dim3 thr(256);
  const dim3 gN((NN + 255)/256), gE((EE + 255)/256);
  const dim3 gGemmBig(313, 4), gGemmSmall(313, 1);
  const dim3 gNode(5000);     // 4 nodes (waves) per block

  for (int r = 0; r < RR; ++r) {
    const int* src = ei + (size_t)r*2*EE;
    const int* dst = src + EE;

    // CSR for this relation (reused by all 4 layers)
    k_zero_int<<<gN, thr, 0, stream>>>(deg, NN);
    k_count  <<<gE, thr, 0, stream>>>(dst, EE, deg);
    k_scan   <<<dim3(1), dim3(1024), 0, stream>>>(deg, off, cur, NN);
    k_scatter<<<gE, thr, 0, stream>>>(src, dst, EE, cur, csr);

    // ---- GATv2 layer 1 ----
    k_gemm<<<gGemmBig, thr, 0, stream>>>(x, Wl1 + (size_t)r*DINC*256, nullptr, nullptr,
                                         nullptr, bufA, NN, 256, 256, 256, 0);
    k_gemm<<<gGemmBig, thr, 0, stream>>>(x, Wr1 + (size_t)r*DINC*256, nullptr, nullptr,
                                         nullptr, bufB, NN, 256, 256, 256, 0);
    k_gat<<<gNode, thr, 0, stream>>>(bufA, bufB, att1 + (size_t)r*256, b1 + (size_t)r*256,
                                     off, csr, bufC, NN);   // bufC = h1 (ReLU'd)

    // ---- GATv2 layer 2 ----
    k_gemm<<<gGemmBig, thr, 0, stream>>>(bufC, Wl2 + (size_t)r*256*256, nullptr, nullptr,
                                         nullptr, bufA, NN, 256, 256, 256, 0);
    k_gemm<<<gGemmBig, thr, 0, stream>>>(bufC, Wr2 + (size_t)r*256*256, nullptr, nullptr,
                                         nullptr, bufB, NN, 256, 256, 256, 0);
    k_gat<<<gNode, thr, 0, stream>>>(bufA, bufB, att2 + (size_t)r*256, b2 + (size_t)r*256,
                                     off, csr, bufC, NN);   // bufC = h2 (overwrite h1)

    // ---- GraphConv layer 3: h3 = relu(agg(h2)@Wrel3 + h2@Wroot3 + b3) ----
    k_agg256<<<gNode, thr, 0, stream>>>(bufC, off, csr, bufA, NN);
    k_gemm<<<gGemmSmall, thr, 0, stream>>>(bufA, Wrel3 + (size_t)r*256*64,
                                           bufC, Wroot3 + (size_t)r*256*64,
                                           b3 + (size_t)r*64, bufB, NN, 256, 64, 64, 1); // bufB = h3 [N,64]

    // ---- GraphConv layer 4: out[:,r,:] = agg(h3)@Wrel4 + h3@Wroot4 + b4 ----
    k_agg64<<<gNode, thr, 0, stream>>>(bufB, off, csr, bufA, NN);   // bufA = agg [N,64]
    k_gemm<<<gGemmSmall, thr, 0, stream>>>(bufA, Wrel4 + (size_t)r*64*64,
                                           bufB, Wroot4 + (size_t)r*64*64,
                                           b4 + (size_t)r*64, out + (size_t)r*64,
                                           NN, 64, 64, RR*OUTC, 0);
  }
}

// Round 2
// 1333.166 us; speedup vs baseline: 1.5434x; 1.5434x over previous
//
#include <hip/hip_runtime.h>
#include <math.h>

#define NN   20000
#define EE   320000
#define RR   4

typedef unsigned short u16;
typedef unsigned int   u32;
typedef __attribute__((ext_vector_type(8))) short short8v;   // 8 bf16 (4 VGPRs)
typedef __attribute__((ext_vector_type(4))) float f32x4;

static __device__ __forceinline__ float lrelu(float v){ return v > 0.f ? v : 0.2f*v; }
static __device__ __forceinline__ float bf2f(u16 u){ return __uint_as_float(((u32)u) << 16); }
static __device__ __forceinline__ u16 f2bf(float f){
  u32 u = __float_as_uint(f);
  u += 0x7fff + ((u >> 16) & 1);        // round-to-nearest-even
  return (u16)(u >> 16);
}
static __device__ __forceinline__ void gload_lds16(const void* g, void* l){
  __builtin_amdgcn_global_load_lds((const __attribute__((address_space(1))) void*)g,
                                   (__attribute__((address_space(3))) void*)l, 16, 0, 0);
}

// ---------------- CSR build ----------------
__global__ void k_zero_int(int* __restrict__ p, int n){
  int i = blockIdx.x*blockDim.x + threadIdx.x;
  if (i < n) p[i] = 0;
}
__global__ void k_count(const int* __restrict__ dst, int e, int* __restrict__ cnt){
  int i = blockIdx.x*blockDim.x + threadIdx.x;
  if (i < e) atomicAdd(&cnt[dst[i]], 1);
}
__global__ __launch_bounds__(1024) void k_scan(const int* __restrict__ cnt, int* __restrict__ off,
                                               int* __restrict__ cur, int n){
  __shared__ int part[1024];
  int t = threadIdx.x;
  int chunk = (n + 1023) >> 10;
  int lo = t*chunk; if (lo > n) lo = n;
  int hi = lo + chunk; if (hi > n) hi = n;
  int s = 0;
  for (int i = lo; i < hi; ++i) s += cnt[i];
  part[t] = s;
  __syncthreads();
  for (int d = 1; d < 1024; d <<= 1) {
    int u = (t >= d) ? part[t-d] : 0;
    __syncthreads();
    part[t] += u;
    __syncthreads();
  }
  int run = (t == 0) ? 0 : part[t-1];
  for (int i = lo; i < hi; ++i) { off[i] = run; cur[i] = run; run += cnt[i]; }
  if (t == 1023) off[n] = part[1023];
}
__global__ void k_scatter(const int* __restrict__ src, const int* __restrict__ dst, int e,
                          int* __restrict__ cur, int* __restrict__ csr){
  int i = blockIdx.x*blockDim.x + threadIdx.x;
  if (i < e) {
    int p = atomicAdd(&cur[dst[i]], 1);
    csr[p] = src[i];
  }
}

// ---------------- prep: f32 -> bf16 cast / transposed-packed weights ----------------
__global__ void k_cast(const float* __restrict__ x, u16* __restrict__ o, int n4){
  int i = blockIdx.x*blockDim.x + threadIdx.x;
  if (i < n4) {
    float4 v = reinterpret_cast<const float4*>(x)[i];
    ushort4 b;
    b.x = f2bf(v.x); b.y = f2bf(v.y); b.z = f2bf(v.z); b.w = f2bf(v.w);
    reinterpret_cast<ushort4*>(o)[i] = b;
  }
}
// dst[r][n][k] bf16 with n in [0,2N): n<N from A (=A^T), else from B. src f32 [r][K][N].
__global__ void k_prep(const float* __restrict__ A, const float* __restrict__ B,
                       u16* __restrict__ dst, int K, int N, int total){
  int i = blockIdx.x*blockDim.x + threadIdx.x;
  if (i >= total) return;
  int k = i % K;
  int n = (i / K) % (2*N);
  int r = i / (K*2*N);
  const float* S = (n < N) ? A : B;
  int nn = (n < N) ? n : n - N;
  dst[i] = f2bf(S[((size_t)r*K + k)*N + nn]);
}

// ---------------- MFMA GEMM: C = act(A0@B0T^T [+ A1@B1T^T] [+bias]) ----------------
// A bf16 [M,K] row-major; BT bf16 [N,K] row-major (= B transposed). BM=128, BK=32.
// 256 threads = 4 waves; wave tile WM x WN; frags 16x16x32. XOR-swizzled LDS (sub ^= row&3).
template<int BN, int WM, int WN>
__global__ __launch_bounds__(256) void k_mfma(
    const u16* __restrict__ A0, const u16* __restrict__ BT0,
    const u16* __restrict__ A1, const u16* __restrict__ BT1,
    const float* __restrict__ bias, int M, int K,
    float* __restrict__ Cf, u16* __restrict__ Cb, int ldc, int relu)
{
  constexpr int BM = 128;
  constexpr int FI = WM/16, FJ = WN/16;
  constexpr int NWC = BN/WN;
  constexpr int ACH = BM*32*2/16/256;   // 16B chunks per thread for A tile
  constexpr int BCH = BN*32*2/16/256;
  __shared__ u16 As[BM*32];
  __shared__ u16 Bs[BN*32];
  const int t = threadIdx.x;
  const int lane = t & 63, wid = t >> 6;
  const int wr = wid / NWC, wc = wid % NWC;
  const int bm = blockIdx.x * BM, bn = blockIdx.y * BN;
  const int lr = lane & 15, lk = lane >> 4;

  f32x4 acc[FI][FJ];
  #pragma unroll
  for (int i = 0; i < FI; ++i)
    #pragma unroll
    for (int j = 0; j < FJ; ++j) acc[i][j] = (f32x4)(0.f);

  const int nk = K >> 5;
  const int tot = A1 ? 2*nk : nk;
  char* AsB = (char*)As;
  char* BsB = (char*)Bs;

  for (int s = 0; s < tot; ++s) {
    const u16* Ap = (s < nk) ? A0 : A1;
    const u16* Bp = (s < nk) ? BT0 : BT1;
    const int kk = ((s < nk) ? s : s - nk) << 5;   // k offset (elems)
    // stage A tile [BM][32] bf16, pre-swizzled source (sub ^ row&3)
    #pragma unroll
    for (int i = 0; i < ACH; ++i) {
      int c = t + 256*i;
      int row = c >> 2, sub = c & 3;
      int lsub = sub ^ (row & 3);
      int grow = bm + row; if (grow >= M) grow = M - 1;
      gload_lds16(Ap + (size_t)grow*K + kk + lsub*8, AsB + c*16);
    }
    #pragma unroll
    for (int i = 0; i < BCH; ++i) {
      int c = t + 256*i;
      int row = c >> 2, sub = c & 3;
      int lsub = sub ^ (row & 3);
      gload_lds16(Bp + (size_t)(bn + row)*K + kk + lsub*8, BsB + c*16);
    }
    __syncthreads();
    short8v a[FI], b[FJ];
    #pragma unroll
    for (int i = 0; i < FI; ++i) {
      int row = wr*WM + i*16 + lr;
      int sub = lk ^ (row & 3);
      a[i] = *reinterpret_cast<short8v*>(AsB + row*64 + sub*16);
    }
    #pragma unroll
    for (int j = 0; j < FJ; ++j) {
      int col = wc*WN + j*16 + lr;
      int sub = lk ^ (col & 3);
      b[j] = *reinterpret_cast<short8v*>(BsB + col*64 + sub*16);
    }
    #pragma unroll
    for (int i = 0; i < FI; ++i)
      #pragma unroll
      for (int j = 0; j < FJ; ++j)
        acc[i][j] = __builtin_amdgcn_mfma_f32_16x16x32_bf16(a[i], b[j], acc[i][j], 0, 0, 0);
    __syncthreads();
  }

  // epilogue: C[row][col], row = bm+wr*WM+i*16+lk*4+q, col = bn+wc*WN+j*16+lr
  #pragma unroll
  for (int i = 0; i < FI; ++i) {
    #pragma unroll
    for (int j = 0; j < FJ; ++j) {
      int col = bn + wc*WN + j*16 + lr;
      float bv = bias ? bias[col] : 0.f;
      #pragma unroll
      for (int q = 0; q < 4; ++q) {
        int row = bm + wr*WM + i*16 + lk*4 + q;
        if (row < M) {
          float v = acc[i][j][q] + bv;
          if (relu) v = fmaxf(v, 0.f);
          if (Cf) Cf[(size_t)row*ldc + col] = v;
          else    Cb[(size_t)row*ldc + col] = f2bf(v);
        }
      }
    }
  }
}

// ---------------- GATv2 attention (bf16 features): one wave per dst node ----------------
// xlr packed [N][512]: cols 0-255 = xl, 256-511 = xr. lane l: head l>>4, ch 4*(l&15)..+3.
__global__ __launch_bounds__(256) void k_gat(
    const u16* __restrict__ xlr, const float* __restrict__ att, const float* __restrict__ bias,
    const int* __restrict__ off, const int* __restrict__ csr,
    u16* __restrict__ out, int n)
{
  int node = blockIdx.x*4 + (threadIdx.x >> 6);
  if (node >= n) return;
  int lane = threadIdx.x & 63;
  ushort4 xr4 = *reinterpret_cast<const ushort4*>(xlr + (size_t)node*512 + 256 + lane*4);
  float xr0 = bf2f(xr4.x), xr1 = bf2f(xr4.y), xr2 = bf2f(xr4.z), xr3 = bf2f(xr4.w);
  const float4 av = *reinterpret_cast<const float4*>(att + lane*4);
  float m = -INFINITY, s = 0.f;
  float a0 = 0.f, a1 = 0.f, a2 = 0.f, a3 = 0.f;
  int e0 = off[node], e1 = off[node+1];
  for (int k = e0 - 1; k < e1; ++k) {        // k = e0-1: implicit self loop
    int src = (k < e0) ? node : csr[k];
    ushort4 x4 = *reinterpret_cast<const ushort4*>(xlr + (size_t)src*512 + lane*4);
    float x0 = bf2f(x4.x), x1 = bf2f(x4.y), x2 = bf2f(x4.z), x3 = bf2f(x4.w);
    float z0 = lrelu(x0 + xr0), z1 = lrelu(x1 + xr1);
    float z2 = lrelu(x2 + xr2), z3 = lrelu(x3 + xr3);
    float part = av.x*z0 + av.y*z1 + av.z*z2 + av.w*z3;
    part += __shfl_xor(part, 1);
    part += __shfl_xor(part, 2);
    part += __shfl_xor(part, 4);
    part += __shfl_xor(part, 8);             // head logit (16-lane group)
    float mn = fmaxf(m, part);
    float sc = __expf(m - mn);
    float pw = __expf(part - mn);
    s  = s*sc + pw;
    a0 = a0*sc + pw*x0;
    a1 = a1*sc + pw*x1;
    a2 = a2*sc + pw*x2;
    a3 = a3*sc + pw*x3;
    m = mn;
  }
  float inv = 1.f / s;
  const float4 bv = *reinterpret_cast<const float4*>(bias + lane*4);
  ushort4 o;
  o.x = f2bf(fmaxf(a0*inv + bv.x, 0.f));     // both GAT layers are followed by ReLU
  o.y = f2bf(fmaxf(a1*inv + bv.y, 0.f));
  o.z = f2bf(fmaxf(a2*inv + bv.z, 0.f));
  o.w = f2bf(fmaxf(a3*inv + bv.w, 0.f));
  *reinterpret_cast<ushort4*>(out + (size_t)node*256 + lane*4) = o;
}

// ---------------- GraphConv neighbor sums ----------------
__global__ __launch_bounds__(256) void k_agg256(const u16* __restrict__ x, const int* __restrict__ off,
                                                const int* __restrict__ csr, u16* __restrict__ out, int n)
{
  int node = blockIdx.x*4 + (threadIdx.x >> 6);
  if (node >= n) return;
  int lane = threadIdx.x & 63;
  float a0 = 0.f, a1 = 0.f, a2 = 0.f, a3 = 0.f;
  int e1 = off[node+1];
  for (int k = off[node]; k < e1; ++k) {
    ushort4 v = *reinterpret_cast<const ushort4*>(x + (size_t)csr[k]*256 + lane*4);
    a0 += bf2f(v.x); a1 += bf2f(v.y); a2 += bf2f(v.z); a3 += bf2f(v.w);
  }
  ushort4 o;
  o.x = f2bf(a0); o.y = f2bf(a1); o.z = f2bf(a2); o.w = f2bf(a3);
  *reinterpret_cast<ushort4*>(out + (size_t)node*256 + lane*4) = o;
}
__global__ __launch_bounds__(256) void k_agg64(const float* __restrict__ x, const int* __restrict__ off,
                                               const int* __restrict__ csr, float* __restrict__ out, int n)
{
  int node = blockIdx.x*4 + (threadIdx.x >> 6);
  if (node >= n) return;
  int lane = threadIdx.x & 63;
  float a = 0.f;
  int e1 = off[node+1];
  for (int k = off[node]; k < e1; ++k) a += x[(size_t)csr[k]*64 + lane];
  out[(size_t)node*64 + lane] = a;
}

// ---------------- f32 vector GEMM (small, K=64) ----------------
#define BK 16
#define LDT 68
__global__ __launch_bounds__(256) void k_gemm(
    const float* __restrict__ A0, const float* __restrict__ B0,
    const float* __restrict__ A1, const float* __restrict__ B1,
    const float* __restrict__ bias, float* __restrict__ C,
    int M, int K, int Nc, int ldc, int relu)
{
  __shared__ float Asm[BK][LDT];
  __shared__ float Bsm[BK][LDT];
  int t  = threadIdx.x;
  int tm = t >> 4, tn = t & 15;
  int bm = blockIdx.x * 64, bn = blockIdx.y * 64;
  float acc[4][4] = {};
  int npair = (A1 != nullptr) ? 2 : 1;
  for (int p = 0; p < npair; ++p) {
    const float* __restrict__ A = p ? A1 : A0;
    const float* __restrict__ B = p ? B1 : B0;
    for (int k0 = 0; k0 < K; k0 += BK) {
      #pragma unroll
      for (int i = 0; i < 4; ++i) {
        int e = t + 256*i;
        int r = e >> 4, c = e & 15;
        int row = bm + r;
        Asm[c][r] = (row < M) ? A[(size_t)row*K + k0 + c] : 0.f;
      }
      #pragma unroll
      for (int i = 0; i < 4; ++i) {
        int e = t + 256*i;
        int r = e >> 6, c = e & 63;
        Bsm[r][c] = B[(size_t)(k0 + r)*Nc + bn + c];
      }
      __syncthreads();
      #pragma unroll
      for (int k = 0; k < BK; ++k) {
        float4 a = *reinterpret_cast<const float4*>(&Asm[k][tm*4]);
        float4 b = *reinterpret_cast<const float4*>(&Bsm[k][tn*4]);
        float av[4] = {a.x, a.y, a.z, a.w};
        float bv[4] = {b.x, b.y, b.z, b.w};
        #pragma unroll
        for (int i = 0; i < 4; ++i)
          #pragma unroll
          for (int j = 0; j < 4; ++j)
            acc[i][j] += av[i]*bv[j];
      }
      __syncthreads();
    }
  }
  #pragma unroll
  for (int i = 0; i < 4; ++i) {
    int row = bm + tm*4 + i;
    if (row >= M) continue;
    float4 o;
    float* po = &o.x;
    #pragma unroll
    for (int j = 0; j < 4; ++j) {
      float v = acc[i][j];
      if (bias) v += bias[bn + tn*4 + j];
      if (relu) v = fmaxf(v, 0.f);
      po[j] = v;
    }
    *reinterpret_cast<float4*>(&C[(size_t)row*ldc + bn + tn*4]) = o;
  }
}

// ---------------- orchestration ----------------
extern "C" void kernel_launch(void* const* d_in, const int* in_sizes, int n_in,
                              void* d_out, int out_size, void* d_ws, size_t ws_size,
                              hipStream_t stream)
{
  const float* x      = (const float*)d_in[0];
  const int*   ei     = (const int*)  d_in[1];
  const float* Wl1    = (const float*)d_in[2];
  const float* Wr1    = (const float*)d_in[3];
  const float* att1   = (const float*)d_in[4];
  const float* b1     = (const float*)d_in[5];
  const float* Wl2    = (const float*)d_in[6];
  const float* Wr2    = (const float*)d_in[7];
  const float* att2   = (const float*)d_in[8];
  const float* b2     = (const float*)d_in[9];
  const float* Wrel3  = (const float*)d_in[10];
  const float* Wroot3 = (const float*)d_in[11];
  const float* b3     = (const float*)d_in[12];
  const float* Wrel4  = (const float*)d_in[13];
  const float* Wroot4 = (const float*)d_in[14];
  const float* b4     = (const float*)d_in[15];
  float* out = (float*)d_out;

  // workspace layout (all 16B aligned)
  u16* XLR = (u16*)d_ws;                         // [NN][512] packed xl|xr
  u16* h   = XLR + (size_t)NN*512;               // [NN][256]
  u16* xbf = h   + (size_t)NN*256;               // [NN][256]
  u16* W1T = xbf + (size_t)NN*256;               // [R][512][256]
  u16* W2T = W1T + (size_t)RR*512*256;
  u16* W3T = W2T + (size_t)RR*512*256;           // [R][128][256] (Wrel3T | Wroot3T)
  int* deg = (int*)(W3T + (size_t)RR*128*256);
  int* off = deg + NN;
  int* cur = off + NN + 1;
  int* csr = cur + NN;
  // L3/L4 scratch aliases XLR (free at that point)
  u16*   aggb = XLR;                             // [NN][256] bf16
  float* h3f  = (float*)(XLR + (size_t)NN*256);  // [NN][64] f32
  float* agg4 = (float*)(XLR + (size_t)NN*256 + (size_t)NN*128); // [NN][64] f32

  const dim3 thr(256);
  const dim3 gN((NN+255)/256), gE((EE+255)/256);
  const dim3 gNode(5000);

  // prep: casts + transposed/packed bf16 weights
  k_cast<<<dim3((NN*256/4+255)/256), thr, 0, stream>>>(x, xbf, NN*256/4);
  k_prep<<<dim3((RR*512*256+255)/256), thr, 0, stream>>>(Wl1, Wr1, W1T, 256, 256, RR*512*256);
  k_prep<<<dim3((RR*512*256+255)/256), thr, 0, stream>>>(Wl2, Wr2, W2T, 256, 256, RR*512*256);
  k_prep<<<dim3((RR*128*256+255)/256), thr, 0, stream>>>(Wrel3, Wroot3, W3T, 256, 64, RR*128*256);

  for (int r = 0; r < RR; ++r) {
    const int* srcp = ei + (size_t)r*2*EE;
    const int* dstp = srcp + EE;

    k_zero_int<<<gN, thr, 0, stream>>>(deg, NN);
    k_count  <<<gE, thr, 0, stream>>>(dstp, EE, deg);
    k_scan   <<<dim3(1), dim3(1024), 0, stream>>>(deg, off, cur, NN);
    k_scatter<<<gE, thr, 0, stream>>>(srcp, dstp, EE, cur, csr);

    // L1: XLR = xbf @ [Wl1|Wr1]   (N=512)
    k_mfma<128,64,64><<<dim3(157,4), thr, 0, stream>>>(
        xbf, W1T + (size_t)r*512*256, nullptr, nullptr,
        nullptr, NN, 256, nullptr, XLR, 512, 0);
    k_gat<<<gNode, thr, 0, stream>>>(XLR, att1 + (size_t)r*256, b1 + (size_t)r*256,
                                     off, csr, h, NN);
    // L2: XLR = h @ [Wl2|Wr2]
    k_mfma<128,64,64><<<dim3(157,4), thr, 0, stream>>>(
        h, W2T + (size_t)r*512*256, nullptr, nullptr,
        nullptr, NN, 256, nullptr, XLR, 512, 0);
    k_gat<<<gNode, thr, 0, stream>>>(XLR, att2 + (size_t)r*256, b2 + (size_t)r*256,
                                     off, csr, h, NN);
    // L3: h3f = relu(agg(h)@Wrel3 + h@Wroot3 + b3)   (N=64, dual pair, f32 out)
    k_agg256<<<gNode, thr, 0, stream>>>(h, off, csr, aggb, NN);
    k_mfma<64,32,64><<<dim3(157,1), thr, 0, stream>>>(
        aggb, W3T + (size_t)r*128*256, h, W3T + (size_t)r*128*256 + 64*256,
        b3 + (size_t)r*64, NN, 256, h3f, nullptr, 64, 1);
    // L4: out[:,r,:] = agg(h3)@Wrel4 + h3@Wroot4 + b4   (f32 vector GEMM, K=64)
    k_agg64<<<gNode, thr, 0, stream>>>(h3f, off, csr, agg4, NN);
    k_gemm<<<dim3(313,1), thr, 0, stream>>>(
        agg4, Wrel4 + (size_t)r*64*64, h3f, Wroot4 + (size_t)r*64*64,
        b4 + (size_t)r*64, out + (size_t)r*64, NN, 64, 64, RR*64, 0);
  }
}

// Round 3
// 899.070 us; speedup vs baseline: 2.2886x; 1.4828x over previous
//
#include <hip/hip_runtime.h>
#include <math.h>

#define NN   20000
#define EE   320000
#define RR   4

typedef unsigned short u16;
typedef unsigned int   u32;
typedef __attribute__((ext_vector_type(8))) short short8v;   // 8 bf16 (4 VGPRs)
typedef __attribute__((ext_vector_type(4))) float f32x4;

static __device__ __forceinline__ float lrelu(float v){ return v > 0.f ? v : 0.2f*v; }
static __device__ __forceinline__ float bf2f(u16 u){ return __uint_as_float(((u32)u) << 16); }
static __device__ __forceinline__ u16 f2bf(float f){
  u32 u = __float_as_uint(f);
  u += 0x7fff + ((u >> 16) & 1);        // round-to-nearest-even
  return (u16)(u >> 16);
}
static __device__ __forceinline__ void gload_lds16(const void* g, void* l){
  __builtin_amdgcn_global_load_lds((const __attribute__((address_space(1))) void*)g,
                                   (__attribute__((address_space(3))) void*)l, 16, 0, 0);
}

// ---------------- CSR build (all 4 relations at once) ----------------
__global__ void k_zero_int(int* __restrict__ p, int n){
  int i = blockIdx.x*blockDim.x + threadIdx.x;
  if (i < n) p[i] = 0;
}
__global__ void k_count4(const int* __restrict__ ei, int* __restrict__ deg4){
  int i = blockIdx.x*blockDim.x + threadIdx.x;
  if (i < RR*EE) {
    int r = i / EE, e = i % EE;
    int d = ei[(size_t)r*2*EE + EE + e];
    atomicAdd(&deg4[r*NN + d], 1);
  }
}
__global__ __launch_bounds__(1024) void k_scan(const int* __restrict__ cnt_all, int* __restrict__ off_all,
                                               int* __restrict__ cur_all, int n){
  const int* cnt = cnt_all + (size_t)blockIdx.x*n;
  int* off = off_all + (size_t)blockIdx.x*(n+1);
  int* cur = cur_all + (size_t)blockIdx.x*n;
  __shared__ int part[1024];
  int t = threadIdx.x;
  int chunk = (n + 1023) >> 10;
  int lo = t*chunk; if (lo > n) lo = n;
  int hi = lo + chunk; if (hi > n) hi = n;
  int s = 0;
  for (int i = lo; i < hi; ++i) s += cnt[i];
  part[t] = s;
  __syncthreads();
  for (int d = 1; d < 1024; d <<= 1) {
    int u = (t >= d) ? part[t-d] : 0;
    __syncthreads();
    part[t] += u;
    __syncthreads();
  }
  int run = (t == 0) ? 0 : part[t-1];
  for (int i = lo; i < hi; ++i) { off[i] = run; cur[i] = run; run += cnt[i]; }
  if (t == 1023) off[n] = part[1023];
}
__global__ void k_scatter4(const int* __restrict__ ei, int* __restrict__ cur4, int* __restrict__ csr4){
  int i = blockIdx.x*blockDim.x + threadIdx.x;
  if (i < RR*EE) {
    int r = i / EE, e = i % EE;
    int s = ei[(size_t)r*2*EE + e];
    int d = ei[(size_t)r*2*EE + EE + e];
    int p = atomicAdd(&cur4[r*NN + d], 1);
    csr4[(size_t)r*EE + p] = s;
  }
}

// ---------------- prep: f32 -> bf16 cast / transposed-packed weights ----------------
__global__ void k_cast(const float* __restrict__ x, u16* __restrict__ o, int n4){
  int i = blockIdx.x*blockDim.x + threadIdx.x;
  if (i < n4) {
    float4 v = reinterpret_cast<const float4*>(x)[i];
    ushort4 b;
    b.x = f2bf(v.x); b.y = f2bf(v.y); b.z = f2bf(v.z); b.w = f2bf(v.w);
    reinterpret_cast<ushort4*>(o)[i] = b;
  }
}
// dst[r][n][k] bf16 with n in [0,2N): n<N from A (=A^T), else from B. src f32 [r][K][N].
__global__ void k_prep(const float* __restrict__ A, const float* __restrict__ B,
                       u16* __restrict__ dst, int K, int N, int total){
  int i = blockIdx.x*blockDim.x + threadIdx.x;
  if (i >= total) return;
  int k = i % K;
  int n = (i / K) % (2*N);
  int r = i / (K*2*N);
  const float* S = (n < N) ? A : B;
  int nn = (n < N) ? n : n - N;
  dst[i] = f2bf(S[((size_t)r*K + k)*N + nn]);
}

// ---------------- MFMA GEMM: C = act(A0@B0T^T [+ A1@B1T^T] [+bias]) ----------------
// A bf16 [M,K] row-major; BT bf16 [N,K] row-major. BM=128, BK=32, 256 thr = 4 waves.
template<int BN, int WM, int WN>
__global__ __launch_bounds__(256) void k_mfma(
    const u16* __restrict__ A0, const u16* __restrict__ BT0,
    const u16* __restrict__ A1, const u16* __restrict__ BT1,
    const float* __restrict__ bias, int M, int K,
    float* __restrict__ Cf, u16* __restrict__ Cb, int ldc, int relu)
{
  constexpr int BM = 128;
  constexpr int FI = WM/16, FJ = WN/16;
  constexpr int NWC = BN/WN;
  constexpr int ACH = BM*32*2/16/256;
  constexpr int BCH = BN*32*2/16/256;
  __shared__ u16 As[BM*32];
  __shared__ u16 Bs[BN*32];
  const int t = threadIdx.x;
  const int lane = t & 63, wid = t >> 6;
  const int wr = wid / NWC, wc = wid % NWC;
  const int bm = blockIdx.x * BM, bn = blockIdx.y * BN;
  const int lr = lane & 15, lk = lane >> 4;

  f32x4 acc[FI][FJ];
  #pragma unroll
  for (int i = 0; i < FI; ++i)
    #pragma unroll
    for (int j = 0; j < FJ; ++j) acc[i][j] = (f32x4)(0.f);

  const int nk = K >> 5;
  const int tot = A1 ? 2*nk : nk;
  char* AsB = (char*)As;
  char* BsB = (char*)Bs;

  for (int s = 0; s < tot; ++s) {
    const u16* Ap = (s < nk) ? A0 : A1;
    const u16* Bp = (s < nk) ? BT0 : BT1;
    const int kk = ((s < nk) ? s : s - nk) << 5;
    #pragma unroll
    for (int i = 0; i < ACH; ++i) {
      int c = t + 256*i;
      int row = c >> 2, sub = c & 3;
      int lsub = sub ^ (row & 3);
      int grow = bm + row; if (grow >= M) grow = M - 1;
      gload_lds16(Ap + (size_t)grow*K + kk + lsub*8, AsB + c*16);
    }
    #pragma unroll
    for (int i = 0; i < BCH; ++i) {
      int c = t + 256*i;
      int row = c >> 2, sub = c & 3;
      int lsub = sub ^ (row & 3);
      gload_lds16(Bp + (size_t)(bn + row)*K + kk + lsub*8, BsB + c*16);
    }
    __syncthreads();
    short8v a[FI], b[FJ];
    #pragma unroll
    for (int i = 0; i < FI; ++i) {
      int row = wr*WM + i*16 + lr;
      int sub = lk ^ (row & 3);
      a[i] = *reinterpret_cast<short8v*>(AsB + row*64 + sub*16);
    }
    #pragma unroll
    for (int j = 0; j < FJ; ++j) {
      int col = wc*WN + j*16 + lr;
      int sub = lk ^ (col & 3);
      b[j] = *reinterpret_cast<short8v*>(BsB + col*64 + sub*16);
    }
    #pragma unroll
    for (int i = 0; i < FI; ++i)
      #pragma unroll
      for (int j = 0; j < FJ; ++j)
        acc[i][j] = __builtin_amdgcn_mfma_f32_16x16x32_bf16(a[i], b[j], acc[i][j], 0, 0, 0);
    __syncthreads();
  }

  #pragma unroll
  for (int i = 0; i < FI; ++i) {
    #pragma unroll
    for (int j = 0; j < FJ; ++j) {
      int col = bn + wc*WN + j*16 + lr;
      float bv = bias ? bias[col] : 0.f;
      #pragma unroll
      for (int q = 0; q < 4; ++q) {
        int row = bm + wr*WM + i*16 + lk*4 + q;
        if (row < M) {
          float v = acc[i][j][q] + bv;
          if (relu) v = fmaxf(v, 0.f);
          if (Cf) Cf[(size_t)row*ldc + col] = v;
          else    Cb[(size_t)row*ldc + col] = f2bf(v);
        }
      }
    }
  }
}

// ---------------- GATv2 attention: one wave per dst, 4-wide edge unroll ----------------
// xlr packed [N][512]: cols 0-255 = xl, 256-511 = xr. lane l: head l>>4, ch 4*(l&15)..+3.
__global__ __launch_bounds__(256) void k_gat(
    const u16* __restrict__ xlr, const float* __restrict__ att, const float* __restrict__ bias,
    const int* __restrict__ off, const int* __restrict__ csr,
    u16* __restrict__ out, int n)
{
  int node = blockIdx.x*4 + (threadIdx.x >> 6);
  if (node >= n) return;
  int lane = threadIdx.x & 63;
  const size_t rowoff = (size_t)lane*4;
  ushort4 xr4 = *reinterpret_cast<const ushort4*>(xlr + (size_t)node*512 + 256 + rowoff);
  const float xr0 = bf2f(xr4.x), xr1 = bf2f(xr4.y), xr2 = bf2f(xr4.z), xr3 = bf2f(xr4.w);
  float4 av = *reinterpret_cast<const float4*>(att + lane*4);
  const float L2E = 1.4426950408889634f;   // logits in log2 domain -> native exp2
  av.x *= L2E; av.y *= L2E; av.z *= L2E; av.w *= L2E;

  // self loop first (always present)
  ushort4 xs = *reinterpret_cast<const ushort4*>(xlr + (size_t)node*512 + rowoff);
  float s0c = bf2f(xs.x), s1c = bf2f(xs.y), s2c = bf2f(xs.z), s3c = bf2f(xs.w);
  float ps = av.x*lrelu(s0c+xr0) + av.y*lrelu(s1c+xr1) + av.z*lrelu(s2c+xr2) + av.w*lrelu(s3c+xr3);
  ps += __shfl_xor(ps, 1);
  ps += __shfl_xor(ps, 2);
  ps += __shfl_xor(ps, 4);
  ps += __shfl_xor(ps, 8);
  float m = ps, s = 1.f;
  float a0 = s0c, a1 = s1c, a2 = s2c, a3 = s3c;

  int k  = off[node];
  const int e1 = off[node+1];
  const int kend = k + ((e1 - k) & ~3);
  for (; k < kend; k += 4) {
    int i0 = csr[k], i1 = csr[k+1], i2 = csr[k+2], i3 = csr[k+3];
    ushort4 v0 = *reinterpret_cast<const ushort4*>(xlr + (size_t)i0*512 + rowoff);
    ushort4 v1 = *reinterpret_cast<const ushort4*>(xlr + (size_t)i1*512 + rowoff);
    ushort4 v2 = *reinterpret_cast<const ushort4*>(xlr + (size_t)i2*512 + rowoff);
    ushort4 v3 = *reinterpret_cast<const ushort4*>(xlr + (size_t)i3*512 + rowoff);
    float x00=bf2f(v0.x), x01=bf2f(v0.y), x02=bf2f(v0.z), x03=bf2f(v0.w);
    float x10=bf2f(v1.x), x11=bf2f(v1.y), x12=bf2f(v1.z), x13=bf2f(v1.w);
    float x20=bf2f(v2.x), x21=bf2f(v2.y), x22=bf2f(v2.z), x23=bf2f(v2.w);
    float x30=bf2f(v3.x), x31=bf2f(v3.y), x32=bf2f(v3.z), x33=bf2f(v3.w);
    float p0 = av.x*lrelu(x00+xr0) + av.y*lrelu(x01+xr1) + av.z*lrelu(x02+xr2) + av.w*lrelu(x03+xr3);
    float p1 = av.x*lrelu(x10+xr0) + av.y*lrelu(x11+xr1) + av.z*lrelu(x12+xr2) + av.w*lrelu(x13+xr3);
    float p2 = av.x*lrelu(x20+xr0) + av.y*lrelu(x21+xr1) + av.z*lrelu(x22+xr2) + av.w*lrelu(x23+xr3);
    float p3 = av.x*lrelu(x30+xr0) + av.y*lrelu(x31+xr1) + av.z*lrelu(x32+xr2) + av.w*lrelu(x33+xr3);
    p0 += __shfl_xor(p0, 1); p1 += __shfl_xor(p1, 1); p2 += __shfl_xor(p2, 1); p3 += __shfl_xor(p3, 1);
    p0 += __shfl_xor(p0, 2); p1 += __shfl_xor(p1, 2); p2 += __shfl_xor(p2, 2); p3 += __shfl_xor(p3, 2);
    p0 += __shfl_xor(p0, 4); p1 += __shfl_xor(p1, 4); p2 += __shfl_xor(p2, 4); p3 += __shfl_xor(p3, 4);
    p0 += __shfl_xor(p0, 8); p1 += __shfl_xor(p1, 8); p2 += __shfl_xor(p2, 8); p3 += __shfl_xor(p3, 8);
    float mn = fmaxf(fmaxf(fmaxf(p0, p1), fmaxf(p2, p3)), m);
    float sc = exp2f(m - mn);
    float w0 = exp2f(p0 - mn), w1 = exp2f(p1 - mn), w2 = exp2f(p2 - mn), w3 = exp2f(p3 - mn);
    s  = s*sc + w0 + w1 + w2 + w3;
    a0 = a0*sc + w0*x00 + w1*x10 + w2*x20 + w3*x30;
    a1 = a1*sc + w0*x01 + w1*x11 + w2*x21 + w3*x31;
    a2 = a2*sc + w0*x02 + w1*x12 + w2*x22 + w3*x32;
    a3 = a3*sc + w0*x03 + w1*x13 + w2*x23 + w3*x33;
    m = mn;
  }
  for (; k < e1; ++k) {          // tail (<=3 edges)
    int si = csr[k];
    ushort4 v = *reinterpret_cast<const ushort4*>(xlr + (size_t)si*512 + rowoff);
    float x0=bf2f(v.x), x1=bf2f(v.y), x2=bf2f(v.z), x3=bf2f(v.w);
    float p = av.x*lrelu(x0+xr0) + av.y*lrelu(x1+xr1) + av.z*lrelu(x2+xr2) + av.w*lrelu(x3+xr3);
    p += __shfl_xor(p, 1);
    p += __shfl_xor(p, 2);
    p += __shfl_xor(p, 4);
    p += __shfl_xor(p, 8);
    float mn = fmaxf(m, p);
    float sc = exp2f(m - mn);
    float w  = exp2f(p - mn);
    s  = s*sc + w;
    a0 = a0*sc + w*x0;
    a1 = a1*sc + w*x1;
    a2 = a2*sc + w*x2;
    a3 = a3*sc + w*x3;
    m = mn;
  }
  float inv = 1.f / s;
  const float4 bv = *reinterpret_cast<const float4*>(bias + lane*4);
  ushort4 o;
  o.x = f2bf(fmaxf(a0*inv + bv.x, 0.f));
  o.y = f2bf(fmaxf(a1*inv + bv.y, 0.f));
  o.z = f2bf(fmaxf(a2*inv + bv.z, 0.f));
  o.w = f2bf(fmaxf(a3*inv + bv.w, 0.f));
  *reinterpret_cast<ushort4*>(out + (size_t)node*256 + lane*4) = o;
}

// ---------------- GraphConv neighbor sums (4-wide) ----------------
__global__ __launch_bounds__(256) void k_agg256(const u16* __restrict__ x, const int* __restrict__ off,
                                                const int* __restrict__ csr, u16* __restrict__ out, int n)
{
  int node = blockIdx.x*4 + (threadIdx.x >> 6);
  if (node >= n) return;
  int lane = threadIdx.x & 63;
  const size_t rowoff = (size_t)lane*4;
  float a0 = 0.f, a1 = 0.f, a2 = 0.f, a3 = 0.f;
  int k = off[node];
  const int e1 = off[node+1];
  const int kend = k + ((e1 - k) & ~3);
  for (; k < kend; k += 4) {
    int i0 = csr[k], i1 = csr[k+1], i2 = csr[k+2], i3 = csr[k+3];
    ushort4 v0 = *reinterpret_cast<const ushort4*>(x + (size_t)i0*256 + rowoff);
    ushort4 v1 = *reinterpret_cast<const ushort4*>(x + (size_t)i1*256 + rowoff);
    ushort4 v2 = *reinterpret_cast<const ushort4*>(x + (size_t)i2*256 + rowoff);
    ushort4 v3 = *reinterpret_cast<const ushort4*>(x + (size_t)i3*256 + rowoff);
    a0 += bf2f(v0.x) + bf2f(v1.x) + bf2f(v2.x) + bf2f(v3.x);
    a1 += bf2f(v0.y) + bf2f(v1.y) + bf2f(v2.y) + bf2f(v3.y);
    a2 += bf2f(v0.z) + bf2f(v1.z) + bf2f(v2.z) + bf2f(v3.z);
    a3 += bf2f(v0.w) + bf2f(v1.w) + bf2f(v2.w) + bf2f(v3.w);
  }
  for (; k < e1; ++k) {
    ushort4 v = *reinterpret_cast<const ushort4*>(x + (size_t)csr[k]*256 + rowoff);
    a0 += bf2f(v.x); a1 += bf2f(v.y); a2 += bf2f(v.z); a3 += bf2f(v.w);
  }
  ushort4 o;
  o.x = f2bf(a0); o.y = f2bf(a1); o.z = f2bf(a2); o.w = f2bf(a3);
  *reinterpret_cast<ushort4*>(out + (size_t)node*256 + rowoff) = o;
}
__global__ __launch_bounds__(256) void k_agg64(const u16* __restrict__ x, const int* __restrict__ off,
                                               const int* __restrict__ csr, u16* __restrict__ out, int n)
{
  int node = blockIdx.x*4 + (threadIdx.x >> 6);
  if (node >= n) return;
  int lane = threadIdx.x & 63;
  float a = 0.f;
  int k = off[node];
  const int e1 = off[node+1];
  const int kend = k + ((e1 - k) & ~3);
  for (; k < kend; k += 4) {
    int i0 = csr[k], i1 = csr[k+1], i2 = csr[k+2], i3 = csr[k+3];
    a += bf2f(x[(size_t)i0*64 + lane]) + bf2f(x[(size_t)i1*64 + lane])
       + bf2f(x[(size_t)i2*64 + lane]) + bf2f(x[(size_t)i3*64 + lane]);
  }
  for (; k < e1; ++k) a += bf2f(x[(size_t)csr[k]*64 + lane]);
  out[(size_t)node*64 + lane] = f2bf(a);
}

// ---------------- orchestration ----------------
extern "C" void kernel_launch(void* const* d_in, const int* in_sizes, int n_in,
                              void* d_out, int out_size, void* d_ws, size_t ws_size,
                              hipStream_t stream)
{
  const float* x      = (const float*)d_in[0];
  const int*   ei     = (const int*)  d_in[1];
  const float* Wl1    = (const float*)d_in[2];
  const float* Wr1    = (const float*)d_in[3];
  const float* att1   = (const float*)d_in[4];
  const float* b1     = (const float*)d_in[5];
  const float* Wl2    = (const float*)d_in[6];
  const float* Wr2    = (const float*)d_in[7];
  const float* att2   = (const float*)d_in[8];
  const float* b2     = (const float*)d_in[9];
  const float* Wrel3  = (const float*)d_in[10];
  const float* Wroot3 = (const float*)d_in[11];
  const float* b3     = (const float*)d_in[12];
  const float* Wrel4  = (const float*)d_in[13];
  const float* Wroot4 = (const float*)d_in[14];
  const float* b4     = (const float*)d_in[15];
  float* out = (float*)d_out;

  // workspace layout
  u16* XLR = (u16*)d_ws;                          // [NN][512]  (also aliased as aggb later)
  u16* h    = XLR + (size_t)NN*512;               // [NN][256]
  u16* xbf  = h   + (size_t)NN*256;               // [NN][256]
  u16* h3b  = xbf + (size_t)NN*256;               // [NN][64]
  u16* ag4b = h3b + (size_t)NN*64;                // [NN][64]
  u16* W1T  = ag4b + (size_t)NN*64;               // [R][512][256]
  u16* W2T  = W1T + (size_t)RR*512*256;           // [R][512][256]
  u16* W3T  = W2T + (size_t)RR*512*256;           // [R][128][256]
  u16* W4T  = W3T + (size_t)RR*128*256;           // [R][128][64]
  int* deg4 = (int*)(W4T + (size_t)RR*128*64);
  int* off4 = deg4 + RR*NN;                       // R*(NN+1)
  int* cur4 = off4 + RR*(NN+1);
  int* csr4 = cur4 + RR*NN;                       // R*EE
  u16* aggb = XLR;                                // [NN][256], reuses XLR

  const dim3 thr(256);

  // prep
  k_cast<<<dim3((NN*256/4+255)/256), thr, 0, stream>>>(x, xbf, NN*256/4);
  k_prep<<<dim3((RR*512*256+255)/256), thr, 0, stream>>>(Wl1, Wr1, W1T, 256, 256, RR*512*256);
  k_prep<<<dim3((RR*512*256+255)/256), thr, 0, stream>>>(Wl2, Wr2, W2T, 256, 256, RR*512*256);
  k_prep<<<dim3((RR*128*256+255)/256), thr, 0, stream>>>(Wrel3, Wroot3, W3T, 256, 64, RR*128*256);
  k_prep<<<dim3((RR*128*64+255)/256),  thr, 0, stream>>>(Wrel4, Wroot4, W4T, 64, 64, RR*128*64);

  // CSR for all relations
  k_zero_int<<<dim3((RR*NN+255)/256), thr, 0, stream>>>(deg4, RR*NN);
  k_count4  <<<dim3((RR*EE+255)/256), thr, 0, stream>>>(ei, deg4);
  k_scan    <<<dim3(RR), dim3(1024), 0, stream>>>(deg4, off4, cur4, NN);
  k_scatter4<<<dim3((RR*EE+255)/256), thr, 0, stream>>>(ei, cur4, csr4);

  const dim3 gNode(5000);
  for (int r = 0; r < RR; ++r) {
    const int* off = off4 + (size_t)r*(NN+1);
    const int* csr = csr4 + (size_t)r*EE;

    // L1: XLR = xbf @ [Wl1|Wr1]
    k_mfma<128,64,64><<<dim3(157,4), thr, 0, stream>>>(
        xbf, W1T + (size_t)r*512*256, nullptr, nullptr,
        nullptr, NN, 256, nullptr, XLR, 512, 0);
    k_gat<<<gNode, thr, 0, stream>>>(XLR, att1 + (size_t)r*256, b1 + (size_t)r*256,
                                     off, csr, h, NN);
    // L2
    k_mfma<128,64,64><<<dim3(157,4), thr, 0, stream>>>(
        h, W2T + (size_t)r*512*256, nullptr, nullptr,
        nullptr, NN, 256, nullptr, XLR, 512, 0);
    k_gat<<<gNode, thr, 0, stream>>>(XLR, att2 + (size_t)r*256, b2 + (size_t)r*256,
                                     off, csr, h, NN);
    // L3: h3b = relu(agg(h)@Wrel3 + h@Wroot3 + b3)  -> bf16 [N,64]
    k_agg256<<<gNode, thr, 0, stream>>>(h, off, csr, aggb, NN);
    k_mfma<64,32,64><<<dim3(157,1), thr, 0, stream>>>(
        aggb, W3T + (size_t)r*128*256, h, W3T + (size_t)r*128*256 + 64*256,
        b3 + (size_t)r*64, NN, 256, nullptr, h3b, 64, 1);
    // L4: out[:,r,:] = agg(h3)@Wrel4 + h3@Wroot4 + b4  (MFMA, K=64, f32 out)
    k_agg64<<<gNode, thr, 0, stream>>>(h3b, off, csr, ag4b, NN);
    k_mfma<64,32,64><<<dim3(157,1), thr, 0, stream>>>(
        ag4b, W4T + (size_t)r*128*64, h3b, W4T + (size_t)r*128*64 + 64*64,
        b4 + (size_t)r*64, NN, 64, out + (size_t)r*64, nullptr, RR*64, 0);
  }
}